// Round 5
// baseline (663.348 us; speedup 1.0000x reference)
//
#include <hip/hip_runtime.h>
#include <hip/hip_bf16.h>

// Problem constants
#define M_TOT   16384      // 8*2048 rows
#define DM      1024       // d_model
#define CD      64         // code_depth
#define NCODES  8192
#define NCHUNK  16         // fallback path code-chunks
#define CPC     (NCODES / NCHUNK)
#define CTILE   16
#define CSPLIT  8          // mfma path code chunks
#define CODES_PER_CHUNK (NCODES / CSPLIT)   // 1024
#define DELTA   2.0f
#define CAP     (1u << 19) // candidate list capacity (524288)

// Output layout (fp32, concatenated in return order)
#define SOFT_OFF  0
#define IDX_OFF   1048576            // 16384*64
#define HARD_OFF  1064960            // + 16384
#define LOSS_OFF  2113536            // + 16384*64

typedef __attribute__((ext_vector_type(8)))  short bfrag;   // 8 bf16 = 4 VGPR
typedef __attribute__((ext_vector_type(16))) float f32x16;  // MFMA 32x32 acc

__device__ __forceinline__ unsigned mapf(float d) {
    unsigned u = __float_as_uint(d);
    return (u & 0x80000000u) ? ~u : (u | 0x80000000u);   // monotone fp32->u32
}
__device__ __forceinline__ float unmapf(unsigned m) {
    unsigned u = (m & 0x80000000u) ? (m ^ 0x80000000u) : ~m;
    return __uint_as_float(u);
}

// ---------------------------------------------------------------------------
// c2[k] = ||book_k||^2  (fixed quad order -> deterministic)
// ---------------------------------------------------------------------------
__global__ __launch_bounds__(256) void compute_c2(const float* __restrict__ book,
                                                  float* __restrict__ c2) {
    const int k = blockIdx.x * 256 + threadIdx.x;
    const float4* p = (const float4*)(book + (size_t)k * CD);
    float s = 0.0f;
#pragma unroll
    for (int q = 0; q < CD / 4; ++q) {
        const float4 v = p[q];
        s = fmaf(v.x, v.x, s); s = fmaf(v.y, v.y, s);
        s = fmaf(v.z, v.z, s); s = fmaf(v.w, v.w, s);
    }
    c2[k] = s;
}

// ---------------------------------------------------------------------------
// fp32 -> bf16 (RTN) conversion, float4 -> ushort4
// ---------------------------------------------------------------------------
__global__ __launch_bounds__(256) void cvt_bf16(const float* __restrict__ src,
                                                unsigned short* __restrict__ dst,
                                                int n4) {
    const int i = blockIdx.x * 256 + threadIdx.x;
    if (i >= n4) return;
    const float4 v = ((const float4*)src)[i];
    ushort4 o;
    __hip_bfloat16 a;
    a = __float2bfloat16(v.x); o.x = *(unsigned short*)&a;
    a = __float2bfloat16(v.y); o.y = *(unsigned short*)&a;
    a = __float2bfloat16(v.z); o.z = *(unsigned short*)&a;
    a = __float2bfloat16(v.w); o.w = *(unsigned short*)&a;
    ((ushort4*)dst)[i] = o;
}

// ---------------------------------------------------------------------------
// soft = x @ W^T + b, fused split-K-in-block (unchanged, passing)
// ---------------------------------------------------------------------------
__global__ __launch_bounds__(1024, 1) void soft_fused(const float* __restrict__ x,
                                                      const float* __restrict__ W,
                                                      const float* __restrict__ bias,
                                                      float* __restrict__ out_soft) {
    __shared__ float smem[8704];
    float (*xt)[16][68] = (float (*)[16][68])smem;
    float (*wt)[16][68] = (float (*)[16][68])(smem + 4352);
    float (*pb)[32][65] = (float (*)[32][65])smem;

    const int tid = threadIdx.x;
    const int kg  = tid >> 8;
    const int t   = tid & 255;
    const int r0  = blockIdx.x * 64;
    const int rg  = t >> 4;
    const int cg  = t & 15;

    float acc[4][4] = {};

    for (int k0 = kg * 256; k0 < kg * 256 + 256; k0 += 16) {
        {
            const int row = t >> 2;
            const int kq  = (t & 3) * 4;
            const float4 v = *(const float4*)(x + (size_t)(r0 + row) * DM + k0 + kq);
            xt[kg][kq + 0][row] = v.x; xt[kg][kq + 1][row] = v.y;
            xt[kg][kq + 2][row] = v.z; xt[kg][kq + 3][row] = v.w;
            const float4 w = *(const float4*)(W + (size_t)row * DM + k0 + kq);
            wt[kg][kq + 0][row] = w.x; wt[kg][kq + 1][row] = w.y;
            wt[kg][kq + 2][row] = w.z; wt[kg][kq + 3][row] = w.w;
        }
        __syncthreads();
#pragma unroll
        for (int kk = 0; kk < 16; ++kk) {
            const float4 xv = *(const float4*)&xt[kg][kk][rg * 4];
            const float4 wv = *(const float4*)&wt[kg][kk][cg * 4];
            const float xa[4] = {xv.x, xv.y, xv.z, xv.w};
            const float wa[4] = {wv.x, wv.y, wv.z, wv.w};
#pragma unroll
            for (int r = 0; r < 4; ++r)
#pragma unroll
                for (int q = 0; q < 4; ++q)
                    acc[r][q] = fmaf(xa[r], wa[q], acc[r][q]);
        }
        __syncthreads();
    }

#pragma unroll
    for (int half = 0; half < 2; ++half) {
        if ((rg >> 3) == half) {
#pragma unroll
            for (int r = 0; r < 4; ++r)
                *(float4*)&pb[kg][(rg & 7) * 4 + r][cg * 4] =
                    make_float4(acc[r][0], acc[r][1], acc[r][2], acc[r][3]);
        }
        __syncthreads();
        if (tid < 512) {
            const int row = tid >> 4;
            const int qd  = tid & 15;
            float4 s = *(const float4*)&pb[0][row][qd * 4];
#pragma unroll
            for (int g = 1; g < 4; ++g) {
                const float4 v = *(const float4*)&pb[g][row][qd * 4];
                s.x += v.x; s.y += v.y; s.z += v.z; s.w += v.w;
            }
            const float4 bb = *(const float4*)(bias + qd * 4);
            s.x += bb.x; s.y += bb.y; s.z += bb.z; s.w += bb.w;
            *(float4*)(out_soft + (size_t)(r0 + half * 32 + row) * CD + qd * 4) = s;
        }
        __syncthreads();
    }
}

// ---------------------------------------------------------------------------
// MFMA distance pass. A = soft rows (32/wave), B = book codes (32/tile).
// D layout (m74/m101-verified): col=lane&31 (code), row=(reg&3)+8*(reg>>2)+4*(lane>>5).
// A/B k-placement uses the SAME guess for both operands -> any k-permutation
// cancels. PASS 1: per-row bf16-min -> mapped-u32 atomicMin.
// PASS 2: collect codes with dist < rowmin + DELTA into list.
// ---------------------------------------------------------------------------
template<int PASS>
__global__ __launch_bounds__(256, 4) void mfma_dist(const unsigned short* __restrict__ sbf,
                                                    const unsigned short* __restrict__ bbf,
                                                    const float* __restrict__ c2,
                                                    unsigned* __restrict__ rowmin_u,
                                                    unsigned* __restrict__ cnt,
                                                    unsigned* __restrict__ list) {
    const int tid  = threadIdx.x;
    const int lane = tid & 63;
    const int w    = tid >> 6;
    const int cl   = lane & 31;
    const int h    = lane >> 5;
    const int r0w  = blockIdx.x * 128 + w * 32;
    const int kbase = blockIdx.y * CODES_PER_CHUNK;

    // A fragments (resident): soft row r0w+cl, k-window km*16 + 8h..+7
    const unsigned short* sp = sbf + (size_t)(r0w + cl) * CD + 8 * h;
    const bfrag a0 = *(const bfrag*)(sp + 0);
    const bfrag a1 = *(const bfrag*)(sp + 16);
    const bfrag a2 = *(const bfrag*)(sp + 32);
    const bfrag a3 = *(const bfrag*)(sp + 48);

    float rmin[16];
    float thr[16];
    if (PASS == 1) {
#pragma unroll
        for (int r = 0; r < 16; ++r) rmin[r] = 3.4e38f;
    } else {
#pragma unroll
        for (int r = 0; r < 16; ++r)
            thr[r] = unmapf(rowmin_u[r0w + (r & 3) + 8 * (r >> 2) + 4 * h]) + DELTA;
    }

#pragma unroll 2
    for (int ct = 0; ct < CODES_PER_CHUNK / 32; ++ct) {
        const int code = kbase + ct * 32 + cl;
        const unsigned short* bp = bbf + (size_t)code * CD + 8 * h;
        const bfrag b0 = *(const bfrag*)(bp + 0);
        const bfrag b1 = *(const bfrag*)(bp + 16);
        const bfrag b2 = *(const bfrag*)(bp + 32);
        const bfrag b3 = *(const bfrag*)(bp + 48);

        f32x16 acc;
#pragma unroll
        for (int r = 0; r < 16; ++r) acc[r] = 0.0f;
        acc = __builtin_amdgcn_mfma_f32_32x32x16_bf16(a0, b0, acc, 0, 0, 0);
        acc = __builtin_amdgcn_mfma_f32_32x32x16_bf16(a1, b1, acc, 0, 0, 0);
        acc = __builtin_amdgcn_mfma_f32_32x32x16_bf16(a2, b2, acc, 0, 0, 0);
        acc = __builtin_amdgcn_mfma_f32_32x32x16_bf16(a3, b3, acc, 0, 0, 0);

        const float cc = c2[code];
        if (PASS == 1) {
#pragma unroll
            for (int r = 0; r < 16; ++r)
                rmin[r] = fminf(rmin[r], fmaf(-2.0f, acc[r], cc));
        } else {
            float hitmin = 1.0e30f;
#pragma unroll
            for (int r = 0; r < 16; ++r)
                hitmin = fminf(hitmin, fmaf(-2.0f, acc[r], cc) - thr[r]);
            if (hitmin < 0.0f) {   // rare
#pragma unroll
                for (int r = 0; r < 16; ++r) {
                    const float dist = fmaf(-2.0f, acc[r], cc);
                    if (dist < thr[r]) {
                        const unsigned row = r0w + (r & 3) + 8 * (r >> 2) + 4 * h;
                        const unsigned idx = atomicAdd(cnt, 1u);
                        if (idx < CAP) list[idx] = (row << 13) | (unsigned)code;
                    }
                }
            }
        }
    }

    if (PASS == 1) {
#pragma unroll
        for (int r = 0; r < 16; ++r) {
            float v = rmin[r];
#pragma unroll
            for (int m = 1; m <= 16; m <<= 1)
                v = fminf(v, __shfl_xor(v, m, 64));
            rmin[r] = v;
        }
        if (cl == 0) {
#pragma unroll
            for (int r = 0; r < 16; ++r)
                atomicMin(&rowmin_u[r0w + (r & 3) + 8 * (r >> 2) + 4 * h], mapf(rmin[r]));
        }
    }
}

// ---------------------------------------------------------------------------
// Exact fp32 rescore of candidates; packed (mapped dist, code) u64 atomicMin
// -> exact argmin with smallest-index tie-break.
// ---------------------------------------------------------------------------
__global__ __launch_bounds__(256) void rescore(const float* __restrict__ soft,
                                               const float* __restrict__ book,
                                               const float* __restrict__ c2,
                                               const unsigned* __restrict__ cnt,
                                               const unsigned* __restrict__ list,
                                               unsigned long long* __restrict__ rowkey) {
    unsigned n = cnt[0];
    if (n > CAP) n = CAP;
    const unsigned i = blockIdx.x * 256 + threadIdx.x;
    if (i >= n) return;
    const unsigned pr = list[i];
    const int row  = pr >> 13;
    const int code = pr & 8191;
    const float4* sp = (const float4*)(soft + (size_t)row * CD);
    const float4* bp = (const float4*)(book + (size_t)code * CD);
    float a = 0.0f;
#pragma unroll
    for (int q = 0; q < 16; ++q) {   // fixed sequential order -> deterministic
        const float4 s = sp[q], b = bp[q];
        a = fmaf(s.x, b.x, a); a = fmaf(s.y, b.y, a);
        a = fmaf(s.z, b.z, a); a = fmaf(s.w, b.w, a);
    }
    const float dist = fmaf(-2.0f, a, c2[code]);
    const unsigned long long key = ((unsigned long long)mapf(dist) << 32) | (unsigned)code;
    atomicMin(&rowkey[row], key);
}

// ---------------------------------------------------------------------------
// finalize (mfma path): idx from rowkey, gather hard, ste, losses
// ---------------------------------------------------------------------------
__global__ __launch_bounds__(256) void finalize2(const float* __restrict__ book,
                                                 const unsigned long long* __restrict__ rowkey,
                                                 float* __restrict__ out) {
    __shared__ int   ksels[16];
    __shared__ float red[256];
    const int tid  = threadIdx.x;
    const int rloc = tid >> 4;
    const int g    = tid & 15;
    const int row  = blockIdx.x * 16 + rloc;

    if (g == 0) {
        const int k = (int)(unsigned)(rowkey[row] & 0xFFFFFFFFull);
        ksels[rloc] = k;
        out[IDX_OFF + row] = (float)k;
    }
    __syncthreads();

    const int k  = ksels[rloc];
    const int dq = g * 4;
    const float4 h = *(const float4*)(book + (size_t)k * CD + dq);
    const float4 s = *(const float4*)(out + SOFT_OFF + (size_t)row * CD + dq);
    const float dx = h.x - s.x, dy = h.y - s.y, dz = h.z - s.z, dw = h.w - s.w;
    float4 ste;
    ste.x = s.x + dx; ste.y = s.y + dy; ste.z = s.z + dz; ste.w = s.w + dw;
    *(float4*)(out + HARD_OFF + (size_t)row * CD + dq) = ste;

    red[tid] = dx * dx + dy * dy + dz * dz + dw * dw;
    __syncthreads();
#pragma unroll
    for (int sh = 128; sh > 0; sh >>= 1) {
        if (tid < sh) red[tid] += red[tid + sh];
        __syncthreads();
    }
    if (tid == 0) {
        const float v = red[0] * (1.0f / (float)(M_TOT * CD));
        atomicAdd(out + LOSS_OFF, v);
        atomicAdd(out + LOSS_OFF + 1, v);
    }
}

// ---------------------------------------------------------------------------
// Fallback kernels (round-2 passing path) for small ws
// ---------------------------------------------------------------------------
__global__ __launch_bounds__(256, 4) void dist_argmin3(const float* __restrict__ soft,
                                                       const float* __restrict__ book,
                                                       const float* __restrict__ c2,
                                                       float* __restrict__ cand_d,
                                                       int* __restrict__ cand_i) {
    const int row   = blockIdx.x * 256 + threadIdx.x;
    const int kbase = blockIdx.y * CPC;
    const float4* sp = (const float4*)(soft + (size_t)row * CD);
    float mind = 3.4e38f;
    int   mini = kbase;
    for (int kt = 0; kt < CPC; kt += CTILE) {
        const float4* bp = (const float4*)(book + (size_t)(kbase + kt) * CD);
        float acc[CTILE] = {};
#pragma unroll
        for (int q = 0; q < 16; ++q) {
            const float4 sv = sp[q];
#pragma unroll
            for (int c = 0; c < CTILE; ++c) {
                const float4 bv = bp[(size_t)c * 16 + q];
                acc[c] = fmaf(sv.x, bv.x, acc[c]); acc[c] = fmaf(sv.y, bv.y, acc[c]);
                acc[c] = fmaf(sv.z, bv.z, acc[c]); acc[c] = fmaf(sv.w, bv.w, acc[c]);
            }
        }
        const int kk0 = kbase + kt;
#pragma unroll
        for (int c = 0; c < CTILE; ++c) {
            const float dd = fmaf(-2.f, acc[c], c2[kk0 + c]);
            if (dd < mind) { mind = dd; mini = kk0 + c; }
        }
    }
    cand_d[blockIdx.y * M_TOT + row] = mind;
    cand_i[blockIdx.y * M_TOT + row] = mini;
}

__global__ __launch_bounds__(256) void finalize_fb(const float* __restrict__ book,
                                                   const float* __restrict__ cand_d,
                                                   const int* __restrict__ cand_i,
                                                   float* __restrict__ out) {
    __shared__ float rd[256];
    __shared__ int   ri[256];
    __shared__ int   ksels[16];
    __shared__ float red[256];
    const int tid  = threadIdx.x;
    const int rloc = tid >> 4;
    const int g    = tid & 15;
    const int row  = blockIdx.x * 16 + rloc;
    rd[tid] = cand_d[(size_t)g * M_TOT + row];
    ri[tid] = cand_i[(size_t)g * M_TOT + row];
    __syncthreads();
    if (g == 0) {
        float bd = rd[rloc * 16];
        int   bi = ri[rloc * 16];
#pragma unroll
        for (int j = 1; j < 16; ++j) {
            const float dd = rd[rloc * 16 + j];
            if (dd < bd) { bd = dd; bi = ri[rloc * 16 + j]; }
        }
        ksels[rloc] = bi;
        out[IDX_OFF + row] = (float)bi;
    }
    __syncthreads();
    const int k  = ksels[rloc];
    const int dq = g * 4;
    const float4 h = *(const float4*)(book + (size_t)k * CD + dq);
    const float4 s = *(const float4*)(out + SOFT_OFF + (size_t)row * CD + dq);
    const float dx = h.x - s.x, dy = h.y - s.y, dz = h.z - s.z, dw = h.w - s.w;
    float4 ste;
    ste.x = s.x + dx; ste.y = s.y + dy; ste.z = s.z + dz; ste.w = s.w + dw;
    *(float4*)(out + HARD_OFF + (size_t)row * CD + dq) = ste;
    red[tid] = dx * dx + dy * dy + dz * dz + dw * dw;
    __syncthreads();
#pragma unroll
    for (int sh = 128; sh > 0; sh >>= 1) {
        if (tid < sh) red[tid] += red[tid + sh];
        __syncthreads();
    }
    if (tid == 0) {
        const float v = red[0] * (1.0f / (float)(M_TOT * CD));
        atomicAdd(out + LOSS_OFF, v);
        atomicAdd(out + LOSS_OFF + 1, v);
    }
}

// ---------------------------------------------------------------------------
extern "C" void kernel_launch(void* const* d_in, const int* in_sizes, int n_in,
                              void* d_out, int out_size, void* d_ws, size_t ws_size,
                              hipStream_t stream) {
    const float* x    = (const float*)d_in[0];
    const float* W    = (const float*)d_in[1];
    const float* bias = (const float*)d_in[2];
    const float* book = (const float*)d_in[3];
    float* out = (float*)d_out;
    char* ws = (char*)d_ws;

    // mfma-path ws layout (16B-aligned offsets)
    unsigned long long* rowkey = (unsigned long long*)(ws);            // 131072 B
    float*    c2       = (float*)(ws + 131072);                        // 32768 B
    unsigned* rowmin_u = (unsigned*)(ws + 163840);                     // 65536 B
    unsigned* cnt      = (unsigned*)(ws + 229376);                     // 256 B
    unsigned short* soft_bf = (unsigned short*)(ws + 229632);          // 2097152 B
    unsigned short* book_bf = (unsigned short*)(ws + 2326784);         // 1048576 B
    unsigned* list     = (unsigned*)(ws + 3375360);                    // 2097152 B
    const size_t NEED  = 5472512;

    hipMemsetAsync(out + LOSS_OFF, 0, 2 * sizeof(float), stream);

    if (ws_size >= NEED) {
        compute_c2<<<NCODES / 256, 256, 0, stream>>>(book, c2);
        cvt_bf16<<<(NCODES * CD / 4 + 255) / 256, 256, 0, stream>>>(book, book_bf,
                                                                    NCODES * CD / 4);
        soft_fused<<<M_TOT / 64, 1024, 0, stream>>>(x, W, bias, out + SOFT_OFF);
        cvt_bf16<<<(M_TOT * CD / 4 + 255) / 256, 256, 0, stream>>>(out + SOFT_OFF, soft_bf,
                                                                   M_TOT * CD / 4);
        hipMemsetAsync(rowmin_u, 0xFF, M_TOT * sizeof(unsigned), stream);
        hipMemsetAsync(rowkey, 0xFF, M_TOT * sizeof(unsigned long long), stream);
        hipMemsetAsync(cnt, 0, 16, stream);

        mfma_dist<1><<<dim3(M_TOT / 128, CSPLIT), 256, 0, stream>>>(soft_bf, book_bf, c2,
                                                                    rowmin_u, cnt, list);
        mfma_dist<2><<<dim3(M_TOT / 128, CSPLIT), 256, 0, stream>>>(soft_bf, book_bf, c2,
                                                                    rowmin_u, cnt, list);
        rescore<<<CAP / 256, 256, 0, stream>>>(out + SOFT_OFF, book, c2, cnt, list, rowkey);
        finalize2<<<M_TOT / 16, 256, 0, stream>>>(book, rowkey, out);
    } else {
        // fallback: round-2 passing path (needs ~2.2 MB)
        float* c2f    = (float*)ws;
        float* cand_d = c2f + NCODES;
        int*   cand_i = (int*)(cand_d + NCHUNK * M_TOT);
        compute_c2<<<NCODES / 256, 256, 0, stream>>>(book, c2f);
        soft_fused<<<M_TOT / 64, 1024, 0, stream>>>(x, W, bias, out + SOFT_OFF);
        dist_argmin3<<<dim3(M_TOT / 256, NCHUNK), 256, 0, stream>>>(out + SOFT_OFF, book,
                                                                    c2f, cand_d, cand_i);
        finalize_fb<<<M_TOT / 16, 256, 0, stream>>>(book, cand_d, cand_i, out);
    }
}

// Round 6
// 615.315 us; speedup vs baseline: 1.0781x; 1.0781x over previous
//
#include <hip/hip_runtime.h>
#include <hip/hip_bf16.h>

// Problem constants
#define M_TOT   16384      // 8*2048 rows
#define DM      1024       // d_model
#define CD      64         // code_depth
#define NCODES  8192
#define NCHUNK  16         // fallback path code-chunks
#define CPC     (NCODES / NCHUNK)
#define CTILE   16
#define CSPLIT  8          // mfma path code chunks
#define CODES_PER_CHUNK (NCODES / CSPLIT)   // 1024
#define DELTA   2.0f
#define CAP     (1u << 19) // candidate list capacity (524288)

// Output layout (fp32, concatenated in return order)
#define SOFT_OFF  0
#define IDX_OFF   1048576            // 16384*64
#define HARD_OFF  1064960            // + 16384
#define LOSS_OFF  2113536            // + 16384*64

typedef __attribute__((ext_vector_type(8)))  short bfrag;   // 8 bf16 = 4 VGPR
typedef __attribute__((ext_vector_type(16))) float f32x16;  // MFMA 32x32 acc

__device__ __forceinline__ unsigned mapf(float d) {
    unsigned u = __float_as_uint(d);
    return (u & 0x80000000u) ? ~u : (u | 0x80000000u);   // monotone fp32->u32
}
__device__ __forceinline__ float unmapf(unsigned m) {
    unsigned u = (m & 0x80000000u) ? (m ^ 0x80000000u) : ~m;
    return __uint_as_float(u);
}
__device__ __forceinline__ unsigned short f2bf(float x) {
    __hip_bfloat16 h = __float2bfloat16(x);   // RTN — must match round-5 cvt
    return *(unsigned short*)&h;
}

// ---------------------------------------------------------------------------
// c2[k] = ||book_k||^2  (fixed quad order -> deterministic)
// ---------------------------------------------------------------------------
__global__ __launch_bounds__(256) void compute_c2(const float* __restrict__ book,
                                                  float* __restrict__ c2) {
    const int k = blockIdx.x * 256 + threadIdx.x;
    const float4* p = (const float4*)(book + (size_t)k * CD);
    float s = 0.0f;
#pragma unroll
    for (int q = 0; q < CD / 4; ++q) {
        const float4 v = p[q];
        s = fmaf(v.x, v.x, s); s = fmaf(v.y, v.y, s);
        s = fmaf(v.z, v.z, s); s = fmaf(v.w, v.w, s);
    }
    c2[k] = s;
}

// ---------------------------------------------------------------------------
// fp32 -> bf16 + MFMA-fragment pack.
// Fragment f of 32-row tile t, lane l=(cl,h): src rows t*32+cl,
// k-window f*16 + 8h .. +7. Dest: packed[((t*4+f)*64 + l)*8] (16 B/thread,
// fully coalesced on both the MFMA-read side and the write side here).
// One thread per fragment chunk.
// ---------------------------------------------------------------------------
__global__ __launch_bounds__(256) void cvt_pack(const float* __restrict__ src,
                                                unsigned short* __restrict__ dst) {
    const int i  = blockIdx.x * 256 + threadIdx.x;
    const int l  = i & 63;
    const int f  = (i >> 6) & 3;
    const int t  = i >> 8;
    const int cl = l & 31, h = l >> 5;
    const float* s = src + (size_t)(t * 32 + cl) * CD + f * 16 + 8 * h;
    const float4 v0 = *(const float4*)(s);
    const float4 v1 = *(const float4*)(s + 4);
    bfrag o;
    o[0] = (short)f2bf(v0.x); o[1] = (short)f2bf(v0.y);
    o[2] = (short)f2bf(v0.z); o[3] = (short)f2bf(v0.w);
    o[4] = (short)f2bf(v1.x); o[5] = (short)f2bf(v1.y);
    o[6] = (short)f2bf(v1.z); o[7] = (short)f2bf(v1.w);
    *(bfrag*)(dst + (size_t)i * 8) = o;
}

// ---------------------------------------------------------------------------
// soft = x @ W^T + b, fused split-K-in-block (unchanged, passing)
// ---------------------------------------------------------------------------
__global__ __launch_bounds__(1024, 1) void soft_fused(const float* __restrict__ x,
                                                      const float* __restrict__ W,
                                                      const float* __restrict__ bias,
                                                      float* __restrict__ out_soft) {
    __shared__ float smem[8704];
    float (*xt)[16][68] = (float (*)[16][68])smem;
    float (*wt)[16][68] = (float (*)[16][68])(smem + 4352);
    float (*pb)[32][65] = (float (*)[32][65])smem;

    const int tid = threadIdx.x;
    const int kg  = tid >> 8;
    const int t   = tid & 255;
    const int r0  = blockIdx.x * 64;
    const int rg  = t >> 4;
    const int cg  = t & 15;

    float acc[4][4] = {};

    for (int k0 = kg * 256; k0 < kg * 256 + 256; k0 += 16) {
        {
            const int row = t >> 2;
            const int kq  = (t & 3) * 4;
            const float4 v = *(const float4*)(x + (size_t)(r0 + row) * DM + k0 + kq);
            xt[kg][kq + 0][row] = v.x; xt[kg][kq + 1][row] = v.y;
            xt[kg][kq + 2][row] = v.z; xt[kg][kq + 3][row] = v.w;
            const float4 w = *(const float4*)(W + (size_t)row * DM + k0 + kq);
            wt[kg][kq + 0][row] = w.x; wt[kg][kq + 1][row] = w.y;
            wt[kg][kq + 2][row] = w.z; wt[kg][kq + 3][row] = w.w;
        }
        __syncthreads();
#pragma unroll
        for (int kk = 0; kk < 16; ++kk) {
            const float4 xv = *(const float4*)&xt[kg][kk][rg * 4];
            const float4 wv = *(const float4*)&wt[kg][kk][cg * 4];
            const float xa[4] = {xv.x, xv.y, xv.z, xv.w};
            const float wa[4] = {wv.x, wv.y, wv.z, wv.w};
#pragma unroll
            for (int r = 0; r < 4; ++r)
#pragma unroll
                for (int q = 0; q < 4; ++q)
                    acc[r][q] = fmaf(xa[r], wa[q], acc[r][q]);
        }
        __syncthreads();
    }

#pragma unroll
    for (int half = 0; half < 2; ++half) {
        if ((rg >> 3) == half) {
#pragma unroll
            for (int r = 0; r < 4; ++r)
                *(float4*)&pb[kg][(rg & 7) * 4 + r][cg * 4] =
                    make_float4(acc[r][0], acc[r][1], acc[r][2], acc[r][3]);
        }
        __syncthreads();
        if (tid < 512) {
            const int row = tid >> 4;
            const int qd  = tid & 15;
            float4 s = *(const float4*)&pb[0][row][qd * 4];
#pragma unroll
            for (int g = 1; g < 4; ++g) {
                const float4 v = *(const float4*)&pb[g][row][qd * 4];
                s.x += v.x; s.y += v.y; s.z += v.z; s.w += v.w;
            }
            const float4 bb = *(const float4*)(bias + qd * 4);
            s.x += bb.x; s.y += bb.y; s.z += bb.z; s.w += bb.w;
            *(float4*)(out_soft + (size_t)(r0 + half * 32 + row) * CD + qd * 4) = s;
        }
        __syncthreads();
    }
}

// ---------------------------------------------------------------------------
// MFMA distance pass over packed fragments. Wave w owns row-tile
// rt = blockIdx.x*4+w (32 rows). All operand loads are lane-contiguous 16B
// (1 KB/instruction, coalesced). Distances bitwise-identical across passes.
// D layout (m74/m101-verified): col=lane&31 (code), row=(reg&3)+8*(reg>>2)+4*h.
// ---------------------------------------------------------------------------
template<int PASS>
__global__ __launch_bounds__(256, 4) void mfma_dist(const unsigned short* __restrict__ ps,
                                                    const unsigned short* __restrict__ pbk,
                                                    const float* __restrict__ c2,
                                                    unsigned* __restrict__ rowmin_u,
                                                    unsigned* __restrict__ cnt,
                                                    unsigned* __restrict__ list) {
    const int tid  = threadIdx.x;
    const int lane = tid & 63;
    const int w    = tid >> 6;
    const int h    = lane >> 5;
    const int cl   = lane & 31;
    const int rt   = blockIdx.x * 4 + w;    // row tile (32 rows)
    const int r0w  = rt * 32;
    const int tbase = blockIdx.y * (CODES_PER_CHUNK / 32);   // first code tile

    // A fragments: 4 coalesced 1KB loads, resident for the whole kernel
    const unsigned short* ap = ps + ((size_t)rt * 4 * 64 + lane) * 8;
    const bfrag a0 = *(const bfrag*)(ap + 0 * 512);
    const bfrag a1 = *(const bfrag*)(ap + 1 * 512);
    const bfrag a2 = *(const bfrag*)(ap + 2 * 512);
    const bfrag a3 = *(const bfrag*)(ap + 3 * 512);

    float rmin[16];
    float thr[16];
    if (PASS == 1) {
#pragma unroll
        for (int r = 0; r < 16; ++r) rmin[r] = 3.4e38f;
    } else {
#pragma unroll
        for (int r = 0; r < 16; ++r)
            thr[r] = unmapf(rowmin_u[r0w + (r & 3) + 8 * (r >> 2) + 4 * h]) + DELTA;
    }

#pragma unroll 2
    for (int ct = 0; ct < CODES_PER_CHUNK / 32; ++ct) {
        const int tile = tbase + ct;
        const unsigned short* bp = pbk + ((size_t)tile * 4 * 64 + lane) * 8;
        const bfrag b0 = *(const bfrag*)(bp + 0 * 512);
        const bfrag b1 = *(const bfrag*)(bp + 1 * 512);
        const bfrag b2 = *(const bfrag*)(bp + 2 * 512);
        const bfrag b3 = *(const bfrag*)(bp + 3 * 512);

        f32x16 acc;
#pragma unroll
        for (int r = 0; r < 16; ++r) acc[r] = 0.0f;
        acc = __builtin_amdgcn_mfma_f32_32x32x16_bf16(a0, b0, acc, 0, 0, 0);
        acc = __builtin_amdgcn_mfma_f32_32x32x16_bf16(a1, b1, acc, 0, 0, 0);
        acc = __builtin_amdgcn_mfma_f32_32x32x16_bf16(a2, b2, acc, 0, 0, 0);
        acc = __builtin_amdgcn_mfma_f32_32x32x16_bf16(a3, b3, acc, 0, 0, 0);

        const int code = tile * 32 + cl;   // D column of this lane
        const float cc = c2[code];
        if (PASS == 1) {
#pragma unroll
            for (int r = 0; r < 16; ++r)
                rmin[r] = fminf(rmin[r], fmaf(-2.0f, acc[r], cc));
        } else {
            float hitmin = 1.0e30f;
#pragma unroll
            for (int r = 0; r < 16; ++r)
                hitmin = fminf(hitmin, fmaf(-2.0f, acc[r], cc) - thr[r]);
            if (hitmin < 0.0f) {   // rare
#pragma unroll
                for (int r = 0; r < 16; ++r) {
                    const float dist = fmaf(-2.0f, acc[r], cc);
                    if (dist < thr[r]) {
                        const unsigned row = r0w + (r & 3) + 8 * (r >> 2) + 4 * h;
                        const unsigned idx = atomicAdd(cnt, 1u);
                        if (idx < CAP) list[idx] = (row << 13) | (unsigned)code;
                    }
                }
            }
        }
    }

    if (PASS == 1) {
#pragma unroll
        for (int r = 0; r < 16; ++r) {
            float v = rmin[r];
#pragma unroll
            for (int m = 1; m <= 16; m <<= 1)
                v = fminf(v, __shfl_xor(v, m, 64));
            rmin[r] = v;
        }
        if (cl == 0) {
#pragma unroll
            for (int r = 0; r < 16; ++r)
                atomicMin(&rowmin_u[r0w + (r & 3) + 8 * (r >> 2) + 4 * h], mapf(rmin[r]));
        }
    }
}

// ---------------------------------------------------------------------------
// Exact fp32 rescore of candidates; packed (mapped dist, code) u64 atomicMin
// -> exact argmin with smallest-index tie-break.
// ---------------------------------------------------------------------------
__global__ __launch_bounds__(256) void rescore(const float* __restrict__ soft,
                                               const float* __restrict__ book,
                                               const float* __restrict__ c2,
                                               const unsigned* __restrict__ cnt,
                                               const unsigned* __restrict__ list,
                                               unsigned long long* __restrict__ rowkey) {
    unsigned n = cnt[0];
    if (n > CAP) n = CAP;
    const unsigned i = blockIdx.x * 256 + threadIdx.x;
    if (i >= n) return;
    const unsigned pr = list[i];
    const int row  = pr >> 13;
    const int code = pr & 8191;
    const float4* sp = (const float4*)(soft + (size_t)row * CD);
    const float4* bp = (const float4*)(book + (size_t)code * CD);
    float a = 0.0f;
#pragma unroll
    for (int q = 0; q < 16; ++q) {   // fixed sequential order -> deterministic
        const float4 s = sp[q], b = bp[q];
        a = fmaf(s.x, b.x, a); a = fmaf(s.y, b.y, a);
        a = fmaf(s.z, b.z, a); a = fmaf(s.w, b.w, a);
    }
    const float dist = fmaf(-2.0f, a, c2[code]);
    const unsigned long long key = ((unsigned long long)mapf(dist) << 32) | (unsigned)code;
    atomicMin(&rowkey[row], key);
}

// ---------------------------------------------------------------------------
// finalize (mfma path): idx from rowkey, gather hard, ste, losses
// ---------------------------------------------------------------------------
__global__ __launch_bounds__(256) void finalize2(const float* __restrict__ book,
                                                 const unsigned long long* __restrict__ rowkey,
                                                 float* __restrict__ out) {
    __shared__ int   ksels[16];
    __shared__ float red[256];
    const int tid  = threadIdx.x;
    const int rloc = tid >> 4;
    const int g    = tid & 15;
    const int row  = blockIdx.x * 16 + rloc;

    if (g == 0) {
        const int k = (int)(unsigned)(rowkey[row] & 0xFFFFFFFFull);
        ksels[rloc] = k;
        out[IDX_OFF + row] = (float)k;
    }
    __syncthreads();

    const int k  = ksels[rloc];
    const int dq = g * 4;
    const float4 h = *(const float4*)(book + (size_t)k * CD + dq);
    const float4 s = *(const float4*)(out + SOFT_OFF + (size_t)row * CD + dq);
    const float dx = h.x - s.x, dy = h.y - s.y, dz = h.z - s.z, dw = h.w - s.w;
    float4 ste;
    ste.x = s.x + dx; ste.y = s.y + dy; ste.z = s.z + dz; ste.w = s.w + dw;
    *(float4*)(out + HARD_OFF + (size_t)row * CD + dq) = ste;

    red[tid] = dx * dx + dy * dy + dz * dz + dw * dw;
    __syncthreads();
#pragma unroll
    for (int sh = 128; sh > 0; sh >>= 1) {
        if (tid < sh) red[tid] += red[tid + sh];
        __syncthreads();
    }
    if (tid == 0) {
        const float v = red[0] * (1.0f / (float)(M_TOT * CD));
        atomicAdd(out + LOSS_OFF, v);
        atomicAdd(out + LOSS_OFF + 1, v);
    }
}

// ---------------------------------------------------------------------------
// Fallback kernels (round-2 passing path) for small ws
// ---------------------------------------------------------------------------
__global__ __launch_bounds__(256, 4) void dist_argmin3(const float* __restrict__ soft,
                                                       const float* __restrict__ book,
                                                       const float* __restrict__ c2,
                                                       float* __restrict__ cand_d,
                                                       int* __restrict__ cand_i) {
    const int row   = blockIdx.x * 256 + threadIdx.x;
    const int kbase = blockIdx.y * CPC;
    const float4* sp = (const float4*)(soft + (size_t)row * CD);
    float mind = 3.4e38f;
    int   mini = kbase;
    for (int kt = 0; kt < CPC; kt += CTILE) {
        const float4* bp = (const float4*)(book + (size_t)(kbase + kt) * CD);
        float acc[CTILE] = {};
#pragma unroll
        for (int q = 0; q < 16; ++q) {
            const float4 sv = sp[q];
#pragma unroll
            for (int c = 0; c < CTILE; ++c) {
                const float4 bv = bp[(size_t)c * 16 + q];
                acc[c] = fmaf(sv.x, bv.x, acc[c]); acc[c] = fmaf(sv.y, bv.y, acc[c]);
                acc[c] = fmaf(sv.z, bv.z, acc[c]); acc[c] = fmaf(sv.w, bv.w, acc[c]);
            }
        }
        const int kk0 = kbase + kt;
#pragma unroll
        for (int c = 0; c < CTILE; ++c) {
            const float dd = fmaf(-2.f, acc[c], c2[kk0 + c]);
            if (dd < mind) { mind = dd; mini = kk0 + c; }
        }
    }
    cand_d[blockIdx.y * M_TOT + row] = mind;
    cand_i[blockIdx.y * M_TOT + row] = mini;
}

__global__ __launch_bounds__(256) void finalize_fb(const float* __restrict__ book,
                                                   const float* __restrict__ cand_d,
                                                   const int* __restrict__ cand_i,
                                                   float* __restrict__ out) {
    __shared__ float rd[256];
    __shared__ int   ri[256];
    __shared__ int   ksels[16];
    __shared__ float red[256];
    const int tid  = threadIdx.x;
    const int rloc = tid >> 4;
    const int g    = tid & 15;
    const int row  = blockIdx.x * 16 + rloc;
    rd[tid] = cand_d[(size_t)g * M_TOT + row];
    ri[tid] = cand_i[(size_t)g * M_TOT + row];
    __syncthreads();
    if (g == 0) {
        float bd = rd[rloc * 16];
        int   bi = ri[rloc * 16];
#pragma unroll
        for (int j = 1; j < 16; ++j) {
            const float dd = rd[rloc * 16 + j];
            if (dd < bd) { bd = dd; bi = ri[rloc * 16 + j]; }
        }
        ksels[rloc] = bi;
        out[IDX_OFF + row] = (float)bi;
    }
    __syncthreads();
    const int k  = ksels[rloc];
    const int dq = g * 4;
    const float4 h = *(const float4*)(book + (size_t)k * CD + dq);
    const float4 s = *(const float4*)(out + SOFT_OFF + (size_t)row * CD + dq);
    const float dx = h.x - s.x, dy = h.y - s.y, dz = h.z - s.z, dw = h.w - s.w;
    float4 ste;
    ste.x = s.x + dx; ste.y = s.y + dy; ste.z = s.z + dz; ste.w = s.w + dw;
    *(float4*)(out + HARD_OFF + (size_t)row * CD + dq) = ste;
    red[tid] = dx * dx + dy * dy + dz * dz + dw * dw;
    __syncthreads();
#pragma unroll
    for (int sh = 128; sh > 0; sh >>= 1) {
        if (tid < sh) red[tid] += red[tid + sh];
        __syncthreads();
    }
    if (tid == 0) {
        const float v = red[0] * (1.0f / (float)(M_TOT * CD));
        atomicAdd(out + LOSS_OFF, v);
        atomicAdd(out + LOSS_OFF + 1, v);
    }
}

// ---------------------------------------------------------------------------
extern "C" void kernel_launch(void* const* d_in, const int* in_sizes, int n_in,
                              void* d_out, int out_size, void* d_ws, size_t ws_size,
                              hipStream_t stream) {
    const float* x    = (const float*)d_in[0];
    const float* W    = (const float*)d_in[1];
    const float* bias = (const float*)d_in[2];
    const float* book = (const float*)d_in[3];
    float* out = (float*)d_out;
    char* ws = (char*)d_ws;

    // mfma-path ws layout (16B-aligned offsets)
    unsigned long long* rowkey = (unsigned long long*)(ws);            // 131072 B
    float*    c2       = (float*)(ws + 131072);                        // 32768 B
    unsigned* rowmin_u = (unsigned*)(ws + 163840);                     // 65536 B
    unsigned* cnt      = (unsigned*)(ws + 229376);                     // 256 B
    unsigned short* soft_pk = (unsigned short*)(ws + 229632);          // 2097152 B
    unsigned short* book_pk = (unsigned short*)(ws + 2326784);         // 1048576 B
    unsigned* list     = (unsigned*)(ws + 3375360);                    // 2097152 B
    const size_t NEED  = 5472512;

    hipMemsetAsync(out + LOSS_OFF, 0, 2 * sizeof(float), stream);

    if (ws_size >= NEED) {
        compute_c2<<<NCODES / 256, 256, 0, stream>>>(book, c2);
        cvt_pack<<<(NCODES / 32) * 4 * 64 / 256, 256, 0, stream>>>(book, book_pk);
        soft_fused<<<M_TOT / 64, 1024, 0, stream>>>(x, W, bias, out + SOFT_OFF);
        cvt_pack<<<(M_TOT / 32) * 4 * 64 / 256, 256, 0, stream>>>(out + SOFT_OFF, soft_pk);
        hipMemsetAsync(rowmin_u, 0xFF, M_TOT * sizeof(unsigned), stream);
        hipMemsetAsync(rowkey, 0xFF, M_TOT * sizeof(unsigned long long), stream);
        hipMemsetAsync(cnt, 0, 16, stream);

        mfma_dist<1><<<dim3(M_TOT / 128, CSPLIT), 256, 0, stream>>>(soft_pk, book_pk, c2,
                                                                    rowmin_u, cnt, list);
        mfma_dist<2><<<dim3(M_TOT / 128, CSPLIT), 256, 0, stream>>>(soft_pk, book_pk, c2,
                                                                    rowmin_u, cnt, list);
        rescore<<<CAP / 256, 256, 0, stream>>>(out + SOFT_OFF, book, c2, cnt, list, rowkey);
        finalize2<<<M_TOT / 16, 256, 0, stream>>>(book, rowkey, out);
    } else {
        // fallback: round-2 passing path (needs ~2.2 MB)
        float* c2f    = (float*)ws;
        float* cand_d = c2f + NCODES;
        int*   cand_i = (int*)(cand_d + NCHUNK * M_TOT);
        compute_c2<<<NCODES / 256, 256, 0, stream>>>(book, c2f);
        soft_fused<<<M_TOT / 64, 1024, 0, stream>>>(x, W, bias, out + SOFT_OFF);
        dist_argmin3<<<dim3(M_TOT / 256, NCHUNK), 256, 0, stream>>>(out + SOFT_OFF, book,
                                                                    c2f, cand_d, cand_i);
        finalize_fb<<<M_TOT / 16, 256, 0, stream>>>(book, cand_d, cand_i, out);
    }
}

// Round 7
// 595.765 us; speedup vs baseline: 1.1134x; 1.0328x over previous
//
#include <hip/hip_runtime.h>
#include <hip/hip_bf16.h>

// Problem constants
#define M_TOT   16384      // 8*2048 rows
#define DM      1024       // d_model
#define CD      64         // code_depth
#define NCODES  8192
#define NCHUNK  16         // fallback path code-chunks
#define CPC     (NCODES / NCHUNK)
#define CTILE   16
#define CSPLIT  8          // mfma path code chunks
#define CODES_PER_CHUNK (NCODES / CSPLIT)   // 1024
#define DELTA   2.0f
#define CAP     (1u << 19) // candidate list capacity (524288)

// Output layout (fp32, concatenated in return order)
#define SOFT_OFF  0
#define IDX_OFF   1048576            // 16384*64
#define HARD_OFF  1064960            // + 16384
#define LOSS_OFF  2113536            // + 16384*64

typedef __attribute__((ext_vector_type(8)))  short bfrag;   // 8 bf16 = 4 VGPR
typedef __attribute__((ext_vector_type(16))) float f32x16;  // MFMA 32x32 acc

__device__ __forceinline__ unsigned mapf(float d) {
    unsigned u = __float_as_uint(d);
    return (u & 0x80000000u) ? ~u : (u | 0x80000000u);   // monotone fp32->u32
}
__device__ __forceinline__ float unmapf(unsigned m) {
    unsigned u = (m & 0x80000000u) ? (m ^ 0x80000000u) : ~m;
    return __uint_as_float(u);
}
__device__ __forceinline__ unsigned short f2bf(float x) {
    __hip_bfloat16 h = __float2bfloat16(x);   // RTN — matches passing rounds
    return *(unsigned short*)&h;
}

// ---------------------------------------------------------------------------
// c2[k] = ||book_k||^2 (exact path) and c2n[k] = -0.5*c2[k] (MFMA acc-init)
// ---------------------------------------------------------------------------
__global__ __launch_bounds__(256) void compute_c2(const float* __restrict__ book,
                                                  float* __restrict__ c2,
                                                  float* __restrict__ c2n) {
    const int k = blockIdx.x * 256 + threadIdx.x;
    const float4* p = (const float4*)(book + (size_t)k * CD);
    float s = 0.0f;
#pragma unroll
    for (int q = 0; q < CD / 4; ++q) {
        const float4 v = p[q];
        s = fmaf(v.x, v.x, s); s = fmaf(v.y, v.y, s);
        s = fmaf(v.z, v.z, s); s = fmaf(v.w, v.w, s);
    }
    c2[k]  = s;
    c2n[k] = -0.5f * s;
}

// ---------------------------------------------------------------------------
// fp32 -> bf16 + MFMA-fragment pack (unchanged from round 6, passing).
// Fragment f of 32-row tile t, lane l=(cl,h): src row t*32+cl,
// k-window f*16 + 8h .. +7. Dest: packed[((t*4+f)*64 + l)*8].
// ---------------------------------------------------------------------------
__global__ __launch_bounds__(256) void cvt_pack(const float* __restrict__ src,
                                                unsigned short* __restrict__ dst) {
    const int i  = blockIdx.x * 256 + threadIdx.x;
    const int l  = i & 63;
    const int f  = (i >> 6) & 3;
    const int t  = i >> 8;
    const int cl = l & 31, h = l >> 5;
    const float* s = src + (size_t)(t * 32 + cl) * CD + f * 16 + 8 * h;
    const float4 v0 = *(const float4*)(s);
    const float4 v1 = *(const float4*)(s + 4);
    bfrag o;
    o[0] = (short)f2bf(v0.x); o[1] = (short)f2bf(v0.y);
    o[2] = (short)f2bf(v0.z); o[3] = (short)f2bf(v0.w);
    o[4] = (short)f2bf(v1.x); o[5] = (short)f2bf(v1.y);
    o[6] = (short)f2bf(v1.z); o[7] = (short)f2bf(v1.w);
    *(bfrag*)(dst + (size_t)i * 8) = o;
}

// ---------------------------------------------------------------------------
// soft = x @ W^T + b, fused split-K-in-block (unchanged, passing)
// ---------------------------------------------------------------------------
__global__ __launch_bounds__(1024, 1) void soft_fused(const float* __restrict__ x,
                                                      const float* __restrict__ W,
                                                      const float* __restrict__ bias,
                                                      float* __restrict__ out_soft) {
    __shared__ float smem[8704];
    float (*xt)[16][68] = (float (*)[16][68])smem;
    float (*wt)[16][68] = (float (*)[16][68])(smem + 4352);
    float (*pb)[32][65] = (float (*)[32][65])smem;

    const int tid = threadIdx.x;
    const int kg  = tid >> 8;
    const int t   = tid & 255;
    const int r0  = blockIdx.x * 64;
    const int rg  = t >> 4;
    const int cg  = t & 15;

    float acc[4][4] = {};

    for (int k0 = kg * 256; k0 < kg * 256 + 256; k0 += 16) {
        {
            const int row = t >> 2;
            const int kq  = (t & 3) * 4;
            const float4 v = *(const float4*)(x + (size_t)(r0 + row) * DM + k0 + kq);
            xt[kg][kq + 0][row] = v.x; xt[kg][kq + 1][row] = v.y;
            xt[kg][kq + 2][row] = v.z; xt[kg][kq + 3][row] = v.w;
            const float4 w = *(const float4*)(W + (size_t)row * DM + k0 + kq);
            wt[kg][kq + 0][row] = w.x; wt[kg][kq + 1][row] = w.y;
            wt[kg][kq + 2][row] = w.z; wt[kg][kq + 3][row] = w.w;
        }
        __syncthreads();
#pragma unroll
        for (int kk = 0; kk < 16; ++kk) {
            const float4 xv = *(const float4*)&xt[kg][kk][rg * 4];
            const float4 wv = *(const float4*)&wt[kg][kk][cg * 4];
            const float xa[4] = {xv.x, xv.y, xv.z, xv.w};
            const float wa[4] = {wv.x, wv.y, wv.z, wv.w};
#pragma unroll
            for (int r = 0; r < 4; ++r)
#pragma unroll
                for (int q = 0; q < 4; ++q)
                    acc[r][q] = fmaf(xa[r], wa[q], acc[r][q]);
        }
        __syncthreads();
    }

#pragma unroll
    for (int half = 0; half < 2; ++half) {
        if ((rg >> 3) == half) {
#pragma unroll
            for (int r = 0; r < 4; ++r)
                *(float4*)&pb[kg][(rg & 7) * 4 + r][cg * 4] =
                    make_float4(acc[r][0], acc[r][1], acc[r][2], acc[r][3]);
        }
        __syncthreads();
        if (tid < 512) {
            const int row = tid >> 4;
            const int qd  = tid & 15;
            float4 s = *(const float4*)&pb[0][row][qd * 4];
#pragma unroll
            for (int g = 1; g < 4; ++g) {
                const float4 v = *(const float4*)&pb[g][row][qd * 4];
                s.x += v.x; s.y += v.y; s.z += v.z; s.w += v.w;
            }
            const float4 bb = *(const float4*)(bias + qd * 4);
            s.x += bb.x; s.y += bb.y; s.z += bb.z; s.w += bb.w;
            *(float4*)(out_soft + (size_t)(r0 + half * 32 + row) * CD + qd * 4) = s;
        }
        __syncthreads();
    }
}

// ---------------------------------------------------------------------------
// MFMA distance pass, SWAPPED operands: A = book codes, B = soft rows.
// D: col (lane&31) = soft row within the wave's 32-row tile; reg r = code
// (r&3)+8*(r>>2)+4*h within the 32-code tile. Per lane the entire running
// state is SCALAR (rmin or thr) — no float[16] arrays, no spill.
// acc is initialized to -c2/2 so dist = -2*acc exactly (monotone).
// ---------------------------------------------------------------------------
template<int PASS>
__global__ __launch_bounds__(256, 4) void mfma_dist(const unsigned short* __restrict__ ps,
                                                    const unsigned short* __restrict__ pbk,
                                                    const float* __restrict__ c2n,
                                                    unsigned* __restrict__ rowmin_u,
                                                    unsigned* __restrict__ cnt,
                                                    unsigned* __restrict__ list) {
    const int tid  = threadIdx.x;
    const int lane = tid & 63;
    const int w    = tid >> 6;
    const int h    = lane >> 5;
    const int cl   = lane & 31;
    const int rt   = blockIdx.x * 4 + w;    // soft row tile (32 rows)
    const int row  = rt * 32 + cl;          // this lane's output row
    const int tbase = blockIdx.y * (CODES_PER_CHUNK / 32);

    // B operand (soft rows), resident: 4 coalesced 1KB loads
    const unsigned short* bp = ps + ((size_t)rt * 256 + lane) * 8;
    const bfrag s0 = *(const bfrag*)(bp + 0 * 512);
    const bfrag s1 = *(const bfrag*)(bp + 1 * 512);
    const bfrag s2 = *(const bfrag*)(bp + 2 * 512);
    const bfrag s3 = *(const bfrag*)(bp + 3 * 512);

    float rmin = 3.4e38f;
    float thr  = 0.0f;
    if (PASS == 2) thr = unmapf(rowmin_u[row]) + DELTA;

    for (int ct = 0; ct < CODES_PER_CHUNK / 32; ++ct) {
        const int tile = tbase + ct;
        const unsigned short* ap = pbk + ((size_t)tile * 256 + lane) * 8;
        const bfrag a0 = *(const bfrag*)(ap + 0 * 512);
        const bfrag a1 = *(const bfrag*)(ap + 1 * 512);
        const bfrag a2 = *(const bfrag*)(ap + 2 * 512);
        const bfrag a3 = *(const bfrag*)(ap + 3 * 512);

        // acc init = -c2/2 for this lane's 16 codes
        const float* cb = c2n + tile * 32 + 4 * h;
        const float4 cq0 = *(const float4*)(cb + 0);
        const float4 cq1 = *(const float4*)(cb + 8);
        const float4 cq2 = *(const float4*)(cb + 16);
        const float4 cq3 = *(const float4*)(cb + 24);
        f32x16 acc;
        acc[0]  = cq0.x; acc[1]  = cq0.y; acc[2]  = cq0.z; acc[3]  = cq0.w;
        acc[4]  = cq1.x; acc[5]  = cq1.y; acc[6]  = cq1.z; acc[7]  = cq1.w;
        acc[8]  = cq2.x; acc[9]  = cq2.y; acc[10] = cq2.z; acc[11] = cq2.w;
        acc[12] = cq3.x; acc[13] = cq3.y; acc[14] = cq3.z; acc[15] = cq3.w;

        acc = __builtin_amdgcn_mfma_f32_32x32x16_bf16(a0, s0, acc, 0, 0, 0);
        acc = __builtin_amdgcn_mfma_f32_32x32x16_bf16(a1, s1, acc, 0, 0, 0);
        acc = __builtin_amdgcn_mfma_f32_32x32x16_bf16(a2, s2, acc, 0, 0, 0);
        acc = __builtin_amdgcn_mfma_f32_32x32x16_bf16(a3, s3, acc, 0, 0, 0);

        // max over the 16 acc regs == min distance (dist = -2*acc)
        float m01 = fmaxf(acc[0],  acc[1]),  m23 = fmaxf(acc[2],  acc[3]);
        float m45 = fmaxf(acc[4],  acc[5]),  m67 = fmaxf(acc[6],  acc[7]);
        float m89 = fmaxf(acc[8],  acc[9]),  mab = fmaxf(acc[10], acc[11]);
        float mcd = fmaxf(acc[12], acc[13]), mef = fmaxf(acc[14], acc[15]);
        float m0 = fmaxf(fmaxf(m01, m23), fmaxf(m45, m67));
        float m1 = fmaxf(fmaxf(m89, mab), fmaxf(mcd, mef));
        const float tilemin = -2.0f * fmaxf(m0, m1);

        if (PASS == 1) {
            rmin = fminf(rmin, tilemin);
        } else {
            if (tilemin < thr) {   // rare
#pragma unroll
                for (int r = 0; r < 16; ++r) {
                    const float d = -2.0f * acc[r];
                    if (d < thr) {
                        const int code = tile * 32 + (r & 3) + 8 * (r >> 2) + 4 * h;
                        const unsigned idx = atomicAdd(cnt, 1u);
                        if (idx < CAP)
                            list[idx] = ((unsigned)row << 13) | (unsigned)code;
                    }
                }
            }
        }
    }

    if (PASS == 1) {
        // combine the two code-halves (lane and lane^32 share the same row)
        rmin = fminf(rmin, __shfl_xor(rmin, 32, 64));
        if (h == 0) atomicMin(&rowmin_u[row], mapf(rmin));
    }
}

// ---------------------------------------------------------------------------
// Exact fp32 rescore of candidates (unchanged, passing); packed
// (mapped dist, code) u64 atomicMin -> exact argmin, smallest-index ties.
// ---------------------------------------------------------------------------
__global__ __launch_bounds__(256) void rescore(const float* __restrict__ soft,
                                               const float* __restrict__ book,
                                               const float* __restrict__ c2,
                                               const unsigned* __restrict__ cnt,
                                               const unsigned* __restrict__ list,
                                               unsigned long long* __restrict__ rowkey) {
    unsigned n = cnt[0];
    if (n > CAP) n = CAP;
    const unsigned i = blockIdx.x * 256 + threadIdx.x;
    if (i >= n) return;
    const unsigned pr = list[i];
    const int row  = pr >> 13;
    const int code = pr & 8191;
    const float4* sp = (const float4*)(soft + (size_t)row * CD);
    const float4* bp = (const float4*)(book + (size_t)code * CD);
    float a = 0.0f;
#pragma unroll
    for (int q = 0; q < 16; ++q) {   // fixed sequential order -> deterministic
        const float4 s = sp[q], b = bp[q];
        a = fmaf(s.x, b.x, a); a = fmaf(s.y, b.y, a);
        a = fmaf(s.z, b.z, a); a = fmaf(s.w, b.w, a);
    }
    const float dist = fmaf(-2.0f, a, c2[code]);
    const unsigned long long key = ((unsigned long long)mapf(dist) << 32) | (unsigned)code;
    atomicMin(&rowkey[row], key);
}

// ---------------------------------------------------------------------------
// finalize (mfma path): idx from rowkey, gather hard, ste, losses
// ---------------------------------------------------------------------------
__global__ __launch_bounds__(256) void finalize2(const float* __restrict__ book,
                                                 const unsigned long long* __restrict__ rowkey,
                                                 float* __restrict__ out) {
    __shared__ int   ksels[16];
    __shared__ float red[256];
    const int tid  = threadIdx.x;
    const int rloc = tid >> 4;
    const int g    = tid & 15;
    const int row  = blockIdx.x * 16 + rloc;

    if (g == 0) {
        const int k = (int)(unsigned)(rowkey[row] & 0xFFFFFFFFull);
        ksels[rloc] = k;
        out[IDX_OFF + row] = (float)k;
    }
    __syncthreads();

    const int k  = ksels[rloc];
    const int dq = g * 4;
    const float4 h = *(const float4*)(book + (size_t)k * CD + dq);
    const float4 s = *(const float4*)(out + SOFT_OFF + (size_t)row * CD + dq);
    const float dx = h.x - s.x, dy = h.y - s.y, dz = h.z - s.z, dw = h.w - s.w;
    float4 ste;
    ste.x = s.x + dx; ste.y = s.y + dy; ste.z = s.z + dz; ste.w = s.w + dw;
    *(float4*)(out + HARD_OFF + (size_t)row * CD + dq) = ste;

    red[tid] = dx * dx + dy * dy + dz * dz + dw * dw;
    __syncthreads();
#pragma unroll
    for (int sh = 128; sh > 0; sh >>= 1) {
        if (tid < sh) red[tid] += red[tid + sh];
        __syncthreads();
    }
    if (tid == 0) {
        const float v = red[0] * (1.0f / (float)(M_TOT * CD));
        atomicAdd(out + LOSS_OFF, v);
        atomicAdd(out + LOSS_OFF + 1, v);
    }
}

// ---------------------------------------------------------------------------
// Fallback kernels (round-2 passing path) for small ws
// ---------------------------------------------------------------------------
__global__ __launch_bounds__(256, 4) void dist_argmin3(const float* __restrict__ soft,
                                                       const float* __restrict__ book,
                                                       const float* __restrict__ c2,
                                                       float* __restrict__ cand_d,
                                                       int* __restrict__ cand_i) {
    const int row   = blockIdx.x * 256 + threadIdx.x;
    const int kbase = blockIdx.y * CPC;
    const float4* sp = (const float4*)(soft + (size_t)row * CD);
    float mind = 3.4e38f;
    int   mini = kbase;
    for (int kt = 0; kt < CPC; kt += CTILE) {
        const float4* bp = (const float4*)(book + (size_t)(kbase + kt) * CD);
        float acc[CTILE] = {};
#pragma unroll
        for (int q = 0; q < 16; ++q) {
            const float4 sv = sp[q];
#pragma unroll
            for (int c = 0; c < CTILE; ++c) {
                const float4 bv = bp[(size_t)c * 16 + q];
                acc[c] = fmaf(sv.x, bv.x, acc[c]); acc[c] = fmaf(sv.y, bv.y, acc[c]);
                acc[c] = fmaf(sv.z, bv.z, acc[c]); acc[c] = fmaf(sv.w, bv.w, acc[c]);
            }
        }
        const int kk0 = kbase + kt;
#pragma unroll
        for (int c = 0; c < CTILE; ++c) {
            const float dd = fmaf(-2.f, acc[c], c2[kk0 + c]);
            if (dd < mind) { mind = dd; mini = kk0 + c; }
        }
    }
    cand_d[blockIdx.y * M_TOT + row] = mind;
    cand_i[blockIdx.y * M_TOT + row] = mini;
}

__global__ __launch_bounds__(256) void finalize_fb(const float* __restrict__ book,
                                                   const float* __restrict__ cand_d,
                                                   const int* __restrict__ cand_i,
                                                   float* __restrict__ out) {
    __shared__ float rd[256];
    __shared__ int   ri[256];
    __shared__ int   ksels[16];
    __shared__ float red[256];
    const int tid  = threadIdx.x;
    const int rloc = tid >> 4;
    const int g    = tid & 15;
    const int row  = blockIdx.x * 16 + rloc;
    rd[tid] = cand_d[(size_t)g * M_TOT + row];
    ri[tid] = cand_i[(size_t)g * M_TOT + row];
    __syncthreads();
    if (g == 0) {
        float bd = rd[rloc * 16];
        int   bi = ri[rloc * 16];
#pragma unroll
        for (int j = 1; j < 16; ++j) {
            const float dd = rd[rloc * 16 + j];
            if (dd < bd) { bd = dd; bi = ri[rloc * 16 + j]; }
        }
        ksels[rloc] = bi;
        out[IDX_OFF + row] = (float)bi;
    }
    __syncthreads();
    const int k  = ksels[rloc];
    const int dq = g * 4;
    const float4 h = *(const float4*)(book + (size_t)k * CD + dq);
    const float4 s = *(const float4*)(out + SOFT_OFF + (size_t)row * CD + dq);
    const float dx = h.x - s.x, dy = h.y - s.y, dz = h.z - s.z, dw = h.w - s.w;
    float4 ste;
    ste.x = s.x + dx; ste.y = s.y + dy; ste.z = s.z + dz; ste.w = s.w + dw;
    *(float4*)(out + HARD_OFF + (size_t)row * CD + dq) = ste;
    red[tid] = dx * dx + dy * dy + dz * dz + dw * dw;
    __syncthreads();
#pragma unroll
    for (int sh = 128; sh > 0; sh >>= 1) {
        if (tid < sh) red[tid] += red[tid + sh];
        __syncthreads();
    }
    if (tid == 0) {
        const float v = red[0] * (1.0f / (float)(M_TOT * CD));
        atomicAdd(out + LOSS_OFF, v);
        atomicAdd(out + LOSS_OFF + 1, v);
    }
}

// ---------------------------------------------------------------------------
extern "C" void kernel_launch(void* const* d_in, const int* in_sizes, int n_in,
                              void* d_out, int out_size, void* d_ws, size_t ws_size,
                              hipStream_t stream) {
    const float* x    = (const float*)d_in[0];
    const float* W    = (const float*)d_in[1];
    const float* bias = (const float*)d_in[2];
    const float* book = (const float*)d_in[3];
    float* out = (float*)d_out;
    char* ws = (char*)d_ws;

    // mfma-path ws layout (16B-aligned offsets)
    unsigned long long* rowkey = (unsigned long long*)(ws);            // 131072 B
    float*    c2       = (float*)(ws + 131072);                        // 32768 B
    float*    c2n      = (float*)(ws + 163840);                        // 32768 B
    unsigned* rowmin_u = (unsigned*)(ws + 196608);                     // 65536 B
    unsigned* cnt      = (unsigned*)(ws + 262144);                     // 256 B
    unsigned short* soft_pk = (unsigned short*)(ws + 262400);          // 2097152 B
    unsigned short* book_pk = (unsigned short*)(ws + 2359552);         // 1048576 B
    unsigned* list     = (unsigned*)(ws + 3408128);                    // 2097152 B
    const size_t NEED  = 5505280;

    hipMemsetAsync(out + LOSS_OFF, 0, 2 * sizeof(float), stream);

    if (ws_size >= NEED) {
        compute_c2<<<NCODES / 256, 256, 0, stream>>>(book, c2, c2n);
        cvt_pack<<<(NCODES / 32) * 4 * 64 / 256, 256, 0, stream>>>(book, book_pk);
        soft_fused<<<M_TOT / 64, 1024, 0, stream>>>(x, W, bias, out + SOFT_OFF);
        cvt_pack<<<(M_TOT / 32) * 4 * 64 / 256, 256, 0, stream>>>(out + SOFT_OFF, soft_pk);
        hipMemsetAsync(rowmin_u, 0xFF, M_TOT * sizeof(unsigned), stream);
        hipMemsetAsync(rowkey, 0xFF, M_TOT * sizeof(unsigned long long), stream);
        hipMemsetAsync(cnt, 0, 16, stream);

        mfma_dist<1><<<dim3(M_TOT / 128, CSPLIT), 256, 0, stream>>>(soft_pk, book_pk, c2n,
                                                                    rowmin_u, cnt, list);
        mfma_dist<2><<<dim3(M_TOT / 128, CSPLIT), 256, 0, stream>>>(soft_pk, book_pk, c2n,
                                                                    rowmin_u, cnt, list);
        rescore<<<CAP / 256, 256, 0, stream>>>(out + SOFT_OFF, book, c2, cnt, list, rowkey);
        finalize2<<<M_TOT / 16, 256, 0, stream>>>(book, rowkey, out);
    } else {
        // fallback: round-2 passing path (needs ~2.2 MB)
        float* c2f    = (float*)ws;
        float* c2nf   = c2f + NCODES;          // unused by fallback dist, harmless
        float* cand_d = c2nf + NCODES;
        int*   cand_i = (int*)(cand_d + NCHUNK * M_TOT);
        compute_c2<<<NCODES / 256, 256, 0, stream>>>(book, c2f, c2nf);
        soft_fused<<<M_TOT / 64, 1024, 0, stream>>>(x, W, bias, out + SOFT_OFF);
        dist_argmin3<<<dim3(M_TOT / 256, NCHUNK), 256, 0, stream>>>(out + SOFT_OFF, book,
                                                                    c2f, cand_d, cand_i);
        finalize_fb<<<M_TOT / 16, 256, 0, stream>>>(book, cand_d, cand_i, out);
    }
}